// Round 5
// baseline (203.514 us; speedup 1.0000x reference)
//
#include <hip/hip_runtime.h>
#include <hip/hip_bf16.h>
#include <math.h>
#include <stdint.h>

typedef __hip_bfloat16 bf16;
typedef __attribute__((ext_vector_type(8))) short short8;
typedef __attribute__((ext_vector_type(4))) float f32x4;
typedef __attribute__((ext_vector_type(16))) float f32x16;

#define NB 2
#define NS 2048
#define ND 1024
#define NH 16
#define NHD 64
#define N3D 3072

// softmax scale folded into exp2 domain: (1/sqrt(64)) * log2(e)
#define SM_SCALE 0.18033688011112042f

// ---------------- async global->LDS, 16B per lane ----------------
__device__ __forceinline__ void gload16(const bf16* g, void* l) {
  __builtin_amdgcn_global_load_lds(
      (const __attribute__((address_space(1))) uint32_t*)g,
      (__attribute__((address_space(3))) uint32_t*)l, 16, 0, 0);
}

// ---------------- fp32 -> bf16 cast (4-wide) ----------------
__global__ void cast_kernel(const float4* __restrict__ in, bf16* __restrict__ out, int n4) {
  int i = blockIdx.x * blockDim.x + threadIdx.x;
  if (i >= n4) return;
  float4 v = in[i];
  alignas(8) bf16 r[4];
  r[0] = __float2bfloat16(v.x);
  r[1] = __float2bfloat16(v.y);
  r[2] = __float2bfloat16(v.z);
  r[3] = __float2bfloat16(v.w);
  *reinterpret_cast<uint2*>(out + (size_t)i * 4) = *reinterpret_cast<const uint2*>(r);
}

// ---------------- bf16 GEMM (m97 structure): C[M,N] = A[M,K] * B[N,K]^T ----------------
template <bool OUT_BF16>
__global__ __launch_bounds__(256) void gemm_bt(const bf16* __restrict__ A,
                                               const bf16* __restrict__ Bm,
                                               void* __restrict__ Cv,
                                               int M, int N, int K) {
  __shared__ short As[128 * 64];
  __shared__ short Bs[128 * 64];
  const int tid = threadIdx.x;
  const int lane = tid & 63;
  const int w = tid >> 6;
  const int wr = w >> 1, wc = w & 1;
  const int l15 = lane & 15, l4 = lane >> 4;
  const int bn0 = blockIdx.x * 128, bm0 = blockIdx.y * 128;
  const int srow = w * 8 + (lane >> 3);
  const int scol = (lane & 7) * 8;
  f32x4 acc[4][4] = {};
  for (int k0 = 0; k0 < K; k0 += 64) {
    __syncthreads();
#pragma unroll
    for (int i = 0; i < 4; ++i) {
      gload16(&A[(size_t)(bm0 + i * 32 + srow) * K + k0 + scol], &As[(i * 32 + w * 8) * 64]);
      gload16(&Bm[(size_t)(bn0 + i * 32 + srow) * K + k0 + scol], &Bs[(i * 32 + w * 8) * 64]);
    }
    __syncthreads();
#pragma unroll
    for (int kk = 0; kk < 64; kk += 32) {
      short8 am[4], bn[4];
#pragma unroll
      for (int t = 0; t < 4; ++t) {
        am[t] = *reinterpret_cast<const short8*>(&As[(wr * 64 + t * 16 + l15) * 64 + kk + l4 * 8]);
        bn[t] = *reinterpret_cast<const short8*>(&Bs[(wc * 64 + t * 16 + l15) * 64 + kk + l4 * 8]);
      }
#pragma unroll
      for (int m = 0; m < 4; ++m)
#pragma unroll
        for (int n = 0; n < 4; ++n)
          acc[m][n] = __builtin_amdgcn_mfma_f32_16x16x32_bf16(am[m], bn[n], acc[m][n], 0, 0, 0);
    }
  }
#pragma unroll
  for (int m = 0; m < 4; ++m)
#pragma unroll
    for (int n = 0; n < 4; ++n)
#pragma unroll
      for (int r = 0; r < 4; ++r) {
        int row = bm0 + wr * 64 + m * 16 + l4 * 4 + r;
        int col = bn0 + wc * 64 + n * 16 + l15;
        if (OUT_BF16)
          reinterpret_cast<bf16*>(Cv)[(size_t)row * N + col] = __float2bfloat16(acc[m][n][r]);
        else
          reinterpret_cast<float*>(Cv)[(size_t)row * N + col] = acc[m][n][r];
      }
}

// ---------------- RoPE ----------------
__global__ void rope_kernel(const bf16* __restrict__ qkv, bf16* __restrict__ Qr,
                            bf16* __restrict__ Kr) {
  int idx = blockIdx.x * blockDim.x + threadIdx.x;
  int j = idx & 31;
  int s = (idx >> 5) & (NS - 1);
  int h = (idx >> 16) & (NH - 1);
  int b = idx >> 20;
  size_t base = (size_t)(b * NS + s) * N3D + h * NHD;
  float q0 = __bfloat162float(qkv[base + j]);
  float q1 = __bfloat162float(qkv[base + j + 32]);
  float k0 = __bfloat162float(qkv[base + ND + j]);
  float k1 = __bfloat162float(qkv[base + ND + j + 32]);
  float inv = exp2f((float)(2 * j) * (-13.287712379549449f / 64.0f));
  float ang = (float)s * inv;
  float sn, cs;
  sincosf(ang, &sn, &cs);
  size_t o = ((size_t)(b * NH + h) * NS + s) * NHD + j;
  Qr[o] = __float2bfloat16(q0 * cs - q1 * sn);
  Qr[o + 32] = __float2bfloat16(q1 * cs + q0 * sn);
  Kr[o] = __float2bfloat16(k0 * cs - k1 * sn);
  Kr[o + 32] = __float2bfloat16(k1 * cs + k0 * sn);
}

// ---------------- V transpose: qkv v-part -> Vt (bf16 [B,H,HD,S]) ----------------
__global__ __launch_bounds__(256) void vtrans_kernel(const bf16* __restrict__ qkv,
                                                     bf16* __restrict__ Vt) {
  int bh = blockIdx.y;
  int b = bh >> 4, h = bh & 15;
  int s0 = blockIdx.x * 64;
  __shared__ bf16 tile[64][72];
#pragma unroll
  for (int it = 0; it < 16; ++it) {
    int e = it * 256 + threadIdx.x;
    int sr = e >> 6, hd = e & 63;
    tile[sr][hd] = qkv[(size_t)(b * NS + s0 + sr) * N3D + 2 * ND + h * NHD + hd];
  }
  __syncthreads();
#pragma unroll
  for (int it = 0; it < 16; ++it) {
    int e = it * 256 + threadIdx.x;
    int hd = e >> 6, sc = e & 63;
    Vt[((size_t)bh * NHD + hd) * NS + s0 + sc] = tile[sc][hd];
  }
}

// ---------------- attn_mask -> float bias ----------------
__global__ void maskbias_kernel(const int* __restrict__ amask, float* __restrict__ mb, int n) {
  int i = blockIdx.x * blockDim.x + threadIdx.x;
  if (i < n) mb[i] = amask[i] ? 0.f : -1e30f;
}

// ---------------- causal flash attention: barrier-free, LDS-free (L2-direct) ------------
// One wave = one 32-row q-tile; 2048 waves = 8/CU all resident; no __syncthreads at all.
// Block = 4 waves of SAME tile length (same t, 4 consecutive bh) -> clean retirement; LPT
// dispatch (longest t first); bh group pinned per XCD slot for L2 locality (~3MB/XCD).
// 32x32 swapped-QK^T; in-register softmax (T12 cvt_pk+permlane32_swap); T13 defer-max.
__global__ __launch_bounds__(256, 2) void attn_kernel(const bf16* __restrict__ Qr,
                                                      const bf16* __restrict__ Kr,
                                                      const bf16* __restrict__ Vt,
                                                      const float* __restrict__ mb,
                                                      bf16* __restrict__ AO) {
  const int tid = threadIdx.x;
  const int lane = tid & 63;
  const int w = tid >> 6;
  const int q = lane & 31;   // q-row (QK) / hd-col (PV)
  const int hi = lane >> 5;

  const int lin = blockIdx.x;        // 0..511
  const int t = 63 - (lin >> 3);     // tile index, longest first
  const int bh = ((lin & 7) << 2) + w;
  const int b = bh >> 4, h = bh & 15;
  const int qw = t * 32;             // q rows [qw, qw+32)
  const int nc = (t + 2) >> 1;       // KV chunks of 64 covering kv <= qw+31

  const bf16* Qb = Qr + (size_t)bh * NS * NHD;
  const bf16* Kb = Kr + (size_t)bh * NS * NHD;
  const bf16* Vb = Vt + (size_t)bh * NHD * NS;
  const float* mbb = mb + b * NS;

  // Q B-frags (col=q, k = s*16 + hi*8 + j)
  short8 Qf[4];
#pragma unroll
  for (int s = 0; s < 4; ++s)
    Qf[s] = *reinterpret_cast<const short8*>(&Qb[(size_t)(qw + q) * NHD + s * 16 + hi * 8]);

  f32x16 o0 = {}, o1 = {};
  float mx = -1e30f, lsum = 0.f;

  for (int c = 0; c < nc; ++c) {
    const int kv0 = c * 64;

    // ---- K A-frags direct from global (L2): row = kv, k = s*16 + hi*8 + j ----
    short8 kf0[4], kf1[4];
#pragma unroll
    for (int s = 0; s < 4; ++s) {
      kf0[s] = *reinterpret_cast<const short8*>(&Kb[(size_t)(kv0 + q) * NHD + s * 16 + hi * 8]);
      kf1[s] =
          *reinterpret_cast<const short8*>(&Kb[(size_t)(kv0 + 32 + q) * NHD + s * 16 + hi * 8]);
    }
    // padding-bias vectors (uniform per half-wave, L1/L2 broadcast)
    float4 bv[2][4];
#pragma unroll
    for (int th = 0; th < 2; ++th)
#pragma unroll
      for (int g = 0; g < 4; ++g)
        bv[th][g] = *reinterpret_cast<const float4*>(&mbb[kv0 + th * 32 + g * 8 + hi * 4]);

    // ---- QK^T swapped: a_t[r] = S[q][kv0 + 32t + crow(r,hi)] ----
    f32x16 a0 = {}, a1 = {};
#pragma unroll
    for (int s = 0; s < 4; ++s) {
      a0 = __builtin_amdgcn_mfma_f32_32x32x16_bf16(kf0[s], Qf[s], a0, 0, 0, 0);
      a1 = __builtin_amdgcn_mfma_f32_32x32x16_bf16(kf1[s], Qf[s], a1, 0, 0, 0);
    }

    // ---- V B-frags direct from global (issued early, consumed after softmax) ----
    short8 vf0[4], vf1[4];
#pragma unroll
    for (int ks = 0; ks < 4; ++ks) {
      vf0[ks] = *reinterpret_cast<const short8*>(&Vb[(size_t)q * NS + kv0 + ks * 16 + hi * 8]);
      vf1[ks] =
          *reinterpret_cast<const short8*>(&Vb[(size_t)(32 + q) * NS + kv0 + ks * 16 + hi * 8]);
    }

    // ---- scale + padding bias + causal (diagonal chunks only) ----
    const int qg = qw + q;
#pragma unroll
    for (int th = 0; th < 2; ++th) {
      f32x16& a = th ? a1 : a0;
      const bool needc = (kv0 + th * 32 + 31 > qw);
#pragma unroll
      for (int r = 0; r < 16; ++r) {
        float v = fmaf(a[r], SM_SCALE, ((const float*)&bv[th][r >> 2])[r & 3]);
        if (needc) {
          int kvg = kv0 + th * 32 + (r & 3) + 8 * (r >> 2) + 4 * hi;
          if (kvg > qg) v = -1e30f;
        }
        a[r] = v;
      }
    }

    // ---- row max: in-lane 32 + cross-half ----
    float cm = fmaxf(a0[0], a0[1]);
#pragma unroll
    for (int r = 2; r < 16; ++r) cm = fmaxf(cm, a0[r]);
#pragma unroll
    for (int r = 0; r < 16; ++r) cm = fmaxf(cm, a1[r]);
    float pm = fmaxf(cm, __shfl_xor(cm, 32));

    // ---- T13 defer-max rescale ----
    if (!__all(pm <= mx + 8.f)) {
      float mn = fmaxf(mx, pm);
      float fac = __builtin_amdgcn_exp2f(mx - mn);
      mx = mn;
      lsum *= fac;
#pragma unroll
      for (int r = 0; r < 16; ++r) {
        float fq = __shfl(fac, (r & 3) + 8 * (r >> 2) + 4 * hi);
        o0[r] *= fq;
        o1[r] *= fq;
      }
    }

    // ---- exp2, row-sum, pack P -> PV A-frags (in-register) ----
    float rs = 0.f;
    short8 pa[4];
#pragma unroll
    for (int th = 0; th < 2; ++th) {
      f32x16& a = th ? a1 : a0;
#pragma unroll
      for (int r = 0; r < 16; ++r) {
        float e = __builtin_amdgcn_exp2f(a[r] - mx);
        a[r] = e;
        rs += e;
      }
#pragma unroll
      for (int g = 0; g < 2; ++g) {
        union { unsigned int u; __hip_bfloat162 h2; } X, X2, Y, Y2;
        X.h2 = __float22bfloat162_rn(float2{a[g * 8 + 0], a[g * 8 + 1]});
        X2.h2 = __float22bfloat162_rn(float2{a[g * 8 + 2], a[g * 8 + 3]});
        Y.h2 = __float22bfloat162_rn(float2{a[g * 8 + 4], a[g * 8 + 5]});
        Y2.h2 = __float22bfloat162_rn(float2{a[g * 8 + 6], a[g * 8 + 7]});
        asm volatile("v_permlane32_swap_b32 %0, %1" : "+v"(X.u), "+v"(Y.u));
        asm volatile("v_permlane32_swap_b32 %0, %1" : "+v"(X2.u), "+v"(Y2.u));
        union { unsigned int u[4]; short8 s; } P;
        P.u[0] = X.u;
        P.u[1] = X2.u;
        P.u[2] = Y.u;
        P.u[3] = Y2.u;
        pa[th * 2 + g] = P.s;
      }
    }
    lsum += rs + __shfl_xor(rs, 32);

    // ---- PV: O[q'][hd] += P * V ----
#pragma unroll
    for (int ks = 0; ks < 4; ++ks) {
      o0 = __builtin_amdgcn_mfma_f32_32x32x16_bf16(pa[ks], vf0[ks], o0, 0, 0, 0);
      o1 = __builtin_amdgcn_mfma_f32_32x32x16_bf16(pa[ks], vf1[ks], o1, 0, 0, 0);
    }
  }

  // ---- epilogue: normalize + write AO [B,S,D] ----
  float inv = 1.0f / lsum;
#pragma unroll
  for (int r = 0; r < 16; ++r) {
    const int crow = (r & 3) + 8 * (r >> 2) + 4 * hi;
    float iq = __shfl(inv, crow);
    size_t base = (size_t)(b * NS + qw + crow) * ND + h * NHD;
    AO[base + q] = __float2bfloat16(o0[r] * iq);
    AO[base + 32 + q] = __float2bfloat16(o1[r] * iq);
  }
}

extern "C" void kernel_launch(void* const* d_in, const int* in_sizes, int n_in,
                              void* d_out, int out_size, void* d_ws, size_t ws_size,
                              hipStream_t stream) {
  const float* x = (const float*)d_in[0];
  const int* amask = (const int*)d_in[1];
  const float* Wqkv = (const float*)d_in[2];
  const float* Wout = (const float*)d_in[3];
  float* out = (float*)d_out;

  char* p = (char*)d_ws;
  bf16* xb = (bf16*)(p);                 // 8,388,608
  bf16* wqkvb = (bf16*)(p + 8388608);    // 6,291,456 (dead after QKV GEMM)
  bf16* woutb = (bf16*)(p + 14680064);   // 2,097,152
  bf16* qkvb = (bf16*)(p + 16777216);    // 25,165,824
  bf16* Qr = (bf16*)(p + 41943040);      // 8,388,608
  bf16* Kr = (bf16*)(p + 50331648);      // 8,388,608
  bf16* Vt = (bf16*)(p + 58720256);      // 8,388,608 -> 67,108,864 end
  bf16* AO = xb;                         // aliases xb (dead after QKV GEMM)
  float* mbias = (float*)(p + 8388608);  // aliases wqkvb (dead after QKV GEMM)

  cast_kernel<<<4096, 256, 0, stream>>>((const float4*)x, xb, (NB * NS * ND) / 4);
  cast_kernel<<<3072, 256, 0, stream>>>((const float4*)Wqkv, wqkvb, (N3D * ND) / 4);
  cast_kernel<<<1024, 256, 0, stream>>>((const float4*)Wout, woutb, (ND * ND) / 4);

  gemm_bt<true><<<dim3(N3D / 128, (NB * NS) / 128), 256, 0, stream>>>(xb, wqkvb, qkvb,
                                                                      NB * NS, N3D, ND);
  rope_kernel<<<(NB * NH * NS * 32) / 256, 256, 0, stream>>>(qkvb, Qr, Kr);
  vtrans_kernel<<<dim3(NS / 64, NB * NH), 256, 0, stream>>>(qkvb, Vt);
  maskbias_kernel<<<16, 256, 0, stream>>>(amask, mbias, NB * NS);
  attn_kernel<<<512, 256, 0, stream>>>(Qr, Kr, Vt, mbias, AO);
  gemm_bt<false><<<dim3(ND / 128, (NB * NS) / 128), 256, 0, stream>>>(AO, woutb, out,
                                                                      NB * NS, ND, ND);
}

// Round 6
// 157.148 us; speedup vs baseline: 1.2951x; 1.2951x over previous
//
#include <hip/hip_runtime.h>
#include <hip/hip_bf16.h>
#include <math.h>
#include <stdint.h>

typedef __hip_bfloat16 bf16;
typedef __attribute__((ext_vector_type(8))) short short8;
typedef __attribute__((ext_vector_type(4))) float f32x4;
typedef __attribute__((ext_vector_type(16))) float f32x16;

#define NB 2
#define NS 2048
#define ND 1024
#define NH 16
#define NHD 64
#define N3D 3072

// softmax scale folded into exp2 domain: (1/sqrt(64)) * log2(e)
#define SM_SCALE 0.18033688011112042f

// ---------------- async global->LDS, 16B per lane ----------------
__device__ __forceinline__ void gload16(const bf16* g, void* l) {
  __builtin_amdgcn_global_load_lds(
      (const __attribute__((address_space(1))) uint32_t*)g,
      (__attribute__((address_space(3))) uint32_t*)l, 16, 0, 0);
}

// ---------------- fp32 -> bf16 cast (4-wide) ----------------
__global__ void cast_kernel(const float4* __restrict__ in, bf16* __restrict__ out, int n4) {
  int i = blockIdx.x * blockDim.x + threadIdx.x;
  if (i >= n4) return;
  float4 v = in[i];
  alignas(8) bf16 r[4];
  r[0] = __float2bfloat16(v.x);
  r[1] = __float2bfloat16(v.y);
  r[2] = __float2bfloat16(v.z);
  r[3] = __float2bfloat16(v.w);
  *reinterpret_cast<uint2*>(out + (size_t)i * 4) = *reinterpret_cast<const uint2*>(r);
}

// ---------------- RoPE cos/sin tables: [S][32] each ----------------
__global__ void ropetab_kernel(float* __restrict__ cs_tab, float* __restrict__ sn_tab) {
  int idx = blockIdx.x * blockDim.x + threadIdx.x;  // 65536
  int j = idx & 31;
  int s = idx >> 5;
  float inv = exp2f((float)(2 * j) * (-13.287712379549449f / 64.0f));
  float ang = (float)s * inv;
  float sn, cs;
  sincosf(ang, &sn, &cs);
  cs_tab[idx] = cs;
  sn_tab[idx] = sn;
}

// ---------------- QKV GEMM with fused RoPE epilogue ----------------
// C = x[4096,1024] @ Wqkv[3072,1024]^T. Q cols [0,1024) -> rope -> Qr [B,H,S,HD];
// K cols [1024,2048) -> rope -> Kr; V cols [2048,3072) -> Vtmp [4096,1024].
__global__ __launch_bounds__(256) void gemm_qkv(const bf16* __restrict__ A,
                                                const bf16* __restrict__ Bm,
                                                const float* __restrict__ cs_tab,
                                                const float* __restrict__ sn_tab,
                                                bf16* __restrict__ Qr, bf16* __restrict__ Kr,
                                                bf16* __restrict__ Vtmp) {
  __shared__ short As[128 * 64];
  __shared__ short Bs[128 * 64];
  const int K = ND;
  const int tid = threadIdx.x;
  const int lane = tid & 63;
  const int w = tid >> 6;
  const int wr = w >> 1, wc = w & 1;
  const int l15 = lane & 15, l4 = lane >> 4;
  const int bn0 = blockIdx.x * 128, bm0 = blockIdx.y * 128;
  const int srow = w * 8 + (lane >> 3);
  const int scol = (lane & 7) * 8;
  f32x4 acc[4][4] = {};
  for (int k0 = 0; k0 < K; k0 += 64) {
    __syncthreads();
#pragma unroll
    for (int i = 0; i < 4; ++i) {
      gload16(&A[(size_t)(bm0 + i * 32 + srow) * K + k0 + scol], &As[(i * 32 + w * 8) * 64]);
      gload16(&Bm[(size_t)(bn0 + i * 32 + srow) * K + k0 + scol], &Bs[(i * 32 + w * 8) * 64]);
    }
    __syncthreads();
#pragma unroll
    for (int kk = 0; kk < 64; kk += 32) {
      short8 am[4], bn[4];
#pragma unroll
      for (int t = 0; t < 4; ++t) {
        am[t] = *reinterpret_cast<const short8*>(&As[(wr * 64 + t * 16 + l15) * 64 + kk + l4 * 8]);
        bn[t] = *reinterpret_cast<const short8*>(&Bs[(wc * 64 + t * 16 + l15) * 64 + kk + l4 * 8]);
      }
#pragma unroll
      for (int m = 0; m < 4; ++m)
#pragma unroll
        for (int n = 0; n < 4; ++n)
          acc[m][n] = __builtin_amdgcn_mfma_f32_16x16x32_bf16(am[m], bn[n], acc[m][n], 0, 0, 0);
    }
  }
  const int colbase = bn0 + wc * 64;  // 64-aligned
  const int region = colbase >> 10;   // 0=Q, 1=K, 2=V
  if (region < 2) {
    bf16* dst = region ? Kr : Qr;
    const int h = (colbase & 1023) >> 6;
#pragma unroll
    for (int m = 0; m < 4; ++m)
#pragma unroll
      for (int n = 0; n < 2; ++n)
#pragma unroll
        for (int r = 0; r < 4; ++r) {
          int row = bm0 + wr * 64 + m * 16 + l4 * 4 + r;
          int b = row >> 11, s = row & (NS - 1);
          int j = n * 16 + l15;  // [0,32)
          float cs = cs_tab[s * 32 + j], sn = sn_tab[s * 32 + j];
          float v0 = acc[m][n][r], v1 = acc[m][n + 2][r];
          size_t base = ((size_t)(b * NH + h) * NS + s) * NHD + j;
          dst[base] = __float2bfloat16(v0 * cs - v1 * sn);
          dst[base + 32] = __float2bfloat16(v1 * cs + v0 * sn);
        }
  } else {
#pragma unroll
    for (int m = 0; m < 4; ++m)
#pragma unroll
      for (int n = 0; n < 4; ++n)
#pragma unroll
        for (int r = 0; r < 4; ++r) {
          int row = bm0 + wr * 64 + m * 16 + l4 * 4 + r;
          int col = colbase + n * 16 + l15 - 2048;
          Vtmp[(size_t)row * ND + col] = __float2bfloat16(acc[m][n][r]);
        }
  }
}

// ---------------- generic bf16 GEMM (out-proj): C[M,N] = A[M,K] * B[N,K]^T ----------------
__global__ __launch_bounds__(256) void gemm_bt(const bf16* __restrict__ A,
                                               const bf16* __restrict__ Bm,
                                               float* __restrict__ Cv,
                                               int M, int N, int K) {
  __shared__ short As[128 * 64];
  __shared__ short Bs[128 * 64];
  const int tid = threadIdx.x;
  const int lane = tid & 63;
  const int w = tid >> 6;
  const int wr = w >> 1, wc = w & 1;
  const int l15 = lane & 15, l4 = lane >> 4;
  const int bn0 = blockIdx.x * 128, bm0 = blockIdx.y * 128;
  const int srow = w * 8 + (lane >> 3);
  const int scol = (lane & 7) * 8;
  f32x4 acc[4][4] = {};
  for (int k0 = 0; k0 < K; k0 += 64) {
    __syncthreads();
#pragma unroll
    for (int i = 0; i < 4; ++i) {
      gload16(&A[(size_t)(bm0 + i * 32 + srow) * K + k0 + scol], &As[(i * 32 + w * 8) * 64]);
      gload16(&Bm[(size_t)(bn0 + i * 32 + srow) * K + k0 + scol], &Bs[(i * 32 + w * 8) * 64]);
    }
    __syncthreads();
#pragma unroll
    for (int kk = 0; kk < 64; kk += 32) {
      short8 am[4], bn[4];
#pragma unroll
      for (int t = 0; t < 4; ++t) {
        am[t] = *reinterpret_cast<const short8*>(&As[(wr * 64 + t * 16 + l15) * 64 + kk + l4 * 8]);
        bn[t] = *reinterpret_cast<const short8*>(&Bs[(wc * 64 + t * 16 + l15) * 64 + kk + l4 * 8]);
      }
#pragma unroll
      for (int m = 0; m < 4; ++m)
#pragma unroll
        for (int n = 0; n < 4; ++n)
          acc[m][n] = __builtin_amdgcn_mfma_f32_16x16x32_bf16(am[m], bn[n], acc[m][n], 0, 0, 0);
    }
  }
#pragma unroll
  for (int m = 0; m < 4; ++m)
#pragma unroll
    for (int n = 0; n < 4; ++n)
#pragma unroll
      for (int r = 0; r < 4; ++r) {
        int row = bm0 + wr * 64 + m * 16 + l4 * 4 + r;
        int col = bn0 + wc * 64 + n * 16 + l15;
        Cv[(size_t)row * N + col] = acc[m][n][r];
      }
}

// ---------------- V transpose: Vtmp [4096,1024] -> Vt (bf16 [B,H,HD,S]) ----------------
__global__ __launch_bounds__(256) void vtrans_kernel(const bf16* __restrict__ Vtmp,
                                                     bf16* __restrict__ Vt) {
  int bh = blockIdx.y;
  int b = bh >> 4, h = bh & 15;
  int s0 = blockIdx.x * 64;
  __shared__ bf16 tile[64][72];
#pragma unroll
  for (int it = 0; it < 16; ++it) {
    int e = it * 256 + threadIdx.x;
    int sr = e >> 6, hd = e & 63;
    tile[sr][hd] = Vtmp[(size_t)(b * NS + s0 + sr) * ND + h * NHD + hd];
  }
  __syncthreads();
#pragma unroll
  for (int it = 0; it < 16; ++it) {
    int e = it * 256 + threadIdx.x;
    int hd = e >> 6, sc = e & 63;
    Vt[((size_t)bh * NHD + hd) * NS + s0 + sc] = tile[sc][hd];
  }
}

// ---------------- attn_mask -> float bias ----------------
__global__ void maskbias_kernel(const int* __restrict__ amask, float* __restrict__ mb, int n) {
  int i = blockIdx.x * blockDim.x + threadIdx.x;
  if (i < n) mb[i] = amask[i] ? 0.f : -1e30f;
}

// ---------------- causal flash attention (round-4 verified structure) ----------------
// 4 waves/block, 32 q-rows/wave (128/block). KVBLK=64, K/V double-buffered LDS with
// T2 XOR swizzle. P in registers (T12 cvt_pk + permlane32_swap). T13 defer-max.
// Grid: 512 linear blocks, XCD-grouped (4 bh per XCD), long tiles first.
__global__ __launch_bounds__(256, 2) void attn_kernel(const bf16* __restrict__ Qr,
                                                      const bf16* __restrict__ Kr,
                                                      const bf16* __restrict__ Vt,
                                                      const float* __restrict__ mb,
                                                      bf16* __restrict__ AO) {
  __shared__ short Ks[2][64 * 64];
  __shared__ short Vs[2][64 * 64];
  __shared__ float Mb[2][64];

  const int tid = threadIdx.x;
  const int lane = tid & 63;
  const int w = tid >> 6;
  const int q = lane & 31;
  const int hi = lane >> 5;

  const int lin = blockIdx.x;
  const int xcd = lin & 7;
  const int k = lin >> 3;
  const int bh = xcd * 4 + (k & 3);
  const int kk = k >> 2;
  const int tile = (k < 32) ? (15 - kk) : (kk - 8);
  const int b = bh >> 4, h = bh & 15;
  const int qw = tile * 128 + w * 32;
  const int nc = 2 * tile + 2;

  const bf16* Qb = Qr + (size_t)bh * NS * NHD;
  const bf16* Kb = Kr + (size_t)bh * NS * NHD;
  const bf16* Vb = Vt + (size_t)bh * NHD * NS;

  const int srow = tid >> 2;
  const int sc0 = (tid & 3) * 16;
  const int swz = (srow & 7) << 3;

  short8 Qf[4];
#pragma unroll
  for (int s = 0; s < 4; ++s)
    Qf[s] = *reinterpret_cast<const short8*>(&Qb[(size_t)(qw + q) * NHD + s * 16 + hi * 8]);

  f32x16 o0 = {}, o1 = {};
  float mx = -1e30f, lsum = 0.f;

  short8 kreg[2], vreg[2];
  float4 mreg;
  auto prefetch = [&](int kv0) {
    kreg[0] = *reinterpret_cast<const short8*>(&Kb[(size_t)(kv0 + srow) * NHD + sc0]);
    kreg[1] = *reinterpret_cast<const short8*>(&Kb[(size_t)(kv0 + srow) * NHD + sc0 + 8]);
    vreg[0] = *reinterpret_cast<const short8*>(&Vb[(size_t)srow * NS + kv0 + sc0]);
    vreg[1] = *reinterpret_cast<const short8*>(&Vb[(size_t)srow * NS + kv0 + sc0 + 8]);
    if (tid < 16) mreg = *reinterpret_cast<const float4*>(&mb[b * NS + kv0 + tid * 4]);
  };
  auto stage = [&](int buf) {
    *reinterpret_cast<short8*>(&Ks[buf][srow * 64 + (sc0 ^ swz)]) = kreg[0];
    *reinterpret_cast<short8*>(&Ks[buf][srow * 64 + ((sc0 + 8) ^ swz)]) = kreg[1];
    *reinterpret_cast<short8*>(&Vs[buf][srow * 64 + (sc0 ^ swz)]) = vreg[0];
    *reinterpret_cast<short8*>(&Vs[buf][srow * 64 + ((sc0 + 8) ^ swz)]) = vreg[1];
    if (tid < 16) *reinterpret_cast<float4*>(&Mb[buf][tid * 4]) = mreg;
  };

  prefetch(0);
  stage(0);
  __syncthreads();

  const int rsw = (q & 7) << 3;

  for (int c = 0; c < nc; ++c) {
    const int cur = c & 1;
    const int kv0 = c * 64;
    if (c + 1 < nc) prefetch((c + 1) * 64);

    if (kv0 < qw + 32) {
      f32x16 a0 = {}, a1 = {};
#pragma unroll
      for (int s = 0; s < 4; ++s) {
        short8 kf0 = *reinterpret_cast<const short8*>(
            &Ks[cur][q * 64 + ((s * 16 + hi * 8) ^ rsw)]);
        short8 kf1 = *reinterpret_cast<const short8*>(
            &Ks[cur][(32 + q) * 64 + ((s * 16 + hi * 8) ^ rsw)]);
        a0 = __builtin_amdgcn_mfma_f32_32x32x16_bf16(kf0, Qf[s], a0, 0, 0, 0);
        a1 = __builtin_amdgcn_mfma_f32_32x32x16_bf16(kf1, Qf[s], a1, 0, 0, 0);
      }

      float4 bv[2][4];
#pragma unroll
      for (int t = 0; t < 2; ++t)
#pragma unroll
        for (int g = 0; g < 4; ++g)
          bv[t][g] = *reinterpret_cast<const float4*>(&Mb[cur][t * 32 + g * 8 + hi * 4]);
      const int qg = qw + q;
#pragma unroll
      for (int t = 0; t < 2; ++t) {
        f32x16& a = t ? a1 : a0;
        const bool needc = (kv0 + t * 32 + 31 > qw);
#pragma unroll
        for (int r = 0; r < 16; ++r) {
          float v = fmaf(a[r], SM_SCALE, ((const float*)&bv[t][r >> 2])[r & 3]);
          if (needc) {
            int kvg = kv0 + t * 32 + (r & 3) + 8 * (r >> 2) + 4 * hi;
            if (kvg > qg) v = -1e30f;
          }
          a[r] = v;
        }
      }

      float cm = a0[0];
#pragma unroll
      for (int r = 1; r < 16; ++r) cm = fmaxf(cm, a0[r]);
#pragma unroll
      for (int r = 0; r < 16; ++r) cm = fmaxf(cm, a1[r]);
      float pm = fmaxf(cm, __shfl_xor(cm, 32));

      if (!__all(pm <= mx + 8.f)) {
        float mn = fmaxf(mx, pm);
        float fac = __builtin_amdgcn_exp2f(mx - mn);
        mx = mn;
        lsum *= fac;
#pragma unroll
        for (int r = 0; r < 16; ++r) {
          float fq = __shfl(fac, (r & 3) + 8 * (r >> 2) + 4 * hi);
          o0[r] *= fq;
          o1[r] *= fq;
        }
      }

      float rs = 0.f;
      short8 pa[4];
#pragma unroll
      for (int t = 0; t < 2; ++t) {
        f32x16& a = t ? a1 : a0;
#pragma unroll
        for (int r = 0; r < 16; ++r) {
          float e = __builtin_amdgcn_exp2f(a[r] - mx);
          a[r] = e;
          rs += e;
        }
#pragma unroll
        for (int g = 0; g < 2; ++g) {
          union { unsigned int u; __hip_bfloat162 h2; } X, X2, Y, Y2;
          X.h2 = __float22bfloat162_rn(float2{a[g * 8 + 0], a[g * 8 + 1]});
          X2.h2 = __float22bfloat162_rn(float2{a[g * 8 + 2], a[g * 8 + 3]});
          Y.h2 = __float22bfloat162_rn(float2{a[g * 8 + 4], a[g * 8 + 5]});
          Y2.h2 = __float22bfloat162_rn(float2{a[g * 8 + 6], a[g * 8 + 7]});
          asm volatile("v_permlane32_swap_b32 %0, %1" : "+v"(X.u), "+v"(Y.u));
          asm volatile("v_permlane32_swap_b32 %0, %1" : "+v"(X2.u), "+v"(Y2.u));
          union { unsigned int u[4]; short8 s; } P;
          P.u[0] = X.u;
          P.u[1] = X2.u;
          P.u[2] = Y.u;
          P.u[3] = Y2.u;
          pa[t * 2 + g] = P.s;
        }
      }
      lsum += rs + __shfl_xor(rs, 32);

#pragma unroll
      for (int ks = 0; ks < 4; ++ks) {
        const int vcol = (ks * 16 + hi * 8) ^ rsw;
        short8 vf0 = *reinterpret_cast<const short8*>(&Vs[cur][q * 64 + vcol]);
        short8 vf1 = *reinterpret_cast<const short8*>(&Vs[cur][(32 + q) * 64 + vcol]);
        o0 = __builtin_amdgcn_mfma_f32_32x32x16_bf16(pa[ks], vf0, o0, 0, 0, 0);
        o1 = __builtin_amdgcn_mfma_f32_32x32x16_bf16(pa[ks], vf1, o1, 0, 0, 0);
      }
    }

    if (c + 1 < nc) stage(cur ^ 1);
    __syncthreads();
  }

  float inv = 1.0f / lsum;
#pragma unroll
  for (int r = 0; r < 16; ++r) {
    const int crow = (r & 3) + 8 * (r >> 2) + 4 * hi;
    float iq = __shfl(inv, crow);
    size_t base = (size_t)(b * NS + qw + crow) * ND + h * NHD;
    AO[base + q] = __float2bfloat16(o0[r] * iq);
    AO[base + 32 + q] = __float2bfloat16(o1[r] * iq);
  }
}

extern "C" void kernel_launch(void* const* d_in, const int* in_sizes, int n_in,
                              void* d_out, int out_size, void* d_ws, size_t ws_size,
                              hipStream_t stream) {
  const float* x = (const float*)d_in[0];
  const int* amask = (const int*)d_in[1];
  const float* Wqkv = (const float*)d_in[2];
  const float* Wout = (const float*)d_in[3];
  float* out = (float*)d_out;

  char* p = (char*)d_ws;
  bf16* xb = (bf16*)(p);                  // 8,388,608
  bf16* wqkvb = (bf16*)(p + 8388608);     // 6,291,456 (dead after gemm_qkv)
  bf16* woutb = (bf16*)(p + 14680064);    // 2,097,152
  bf16* Vtmp = (bf16*)(p + 16777216);     // 8,388,608 -> 25,165,824
  float* cs_tab = (float*)(p + 25165824); // 262,144
  float* sn_tab = (float*)(p + 25427968); // 262,144 -> 25,690,112
  bf16* Qr = (bf16*)(p + 41943040);       // 8,388,608
  bf16* Kr = (bf16*)(p + 50331648);       // 8,388,608
  bf16* Vt = (bf16*)(p + 58720256);       // 8,388,608 -> 67,108,864 end
  bf16* AO = xb;                          // aliases xb (dead after gemm_qkv)
  float* mbias = (float*)(p + 8388608);   // aliases wqkvb (dead after gemm_qkv)

  cast_kernel<<<4096, 256, 0, stream>>>((const float4*)x, xb, (NB * NS * ND) / 4);
  cast_kernel<<<3072, 256, 0, stream>>>((const float4*)Wqkv, wqkvb, (N3D * ND) / 4);
  cast_kernel<<<1024, 256, 0, stream>>>((const float4*)Wout, woutb, (ND * ND) / 4);
  ropetab_kernel<<<256, 256, 0, stream>>>(cs_tab, sn_tab);

  gemm_qkv<<<dim3(N3D / 128, (NB * NS) / 128), 256, 0, stream>>>(xb, wqkvb, cs_tab, sn_tab,
                                                                 Qr, Kr, Vtmp);
  vtrans_kernel<<<dim3(NS / 64, NB * NH), 256, 0, stream>>>(Vtmp, Vt);
  maskbias_kernel<<<16, 256, 0, stream>>>(amask, mbias, NB * NS);
  attn_kernel<<<512, 256, 0, stream>>>(Qr, Kr, Vt, mbias, AO);
  gemm_bt<<<dim3(ND / 128, (NB * NS) / 128), 256, 0, stream>>>(AO, woutb, out,
                                                               NB * NS, ND, ND);
}